// Round 14
// baseline (80.832 us; speedup 1.0000x reference)
//
#include <hip/hip_runtime.h>
#include <cstdint>
#include <cstddef>

#define IN_F 4096
#define OUT_F 4096
#define NROWS 8192
#define PI_F 3.14159265358979323846f

// padded complex index (breaks power-of-2 bank strides; injective)
#define PD(a) ((a) + ((a) >> 4))

__device__ inline float2 cmul(float2 a, float2 b) {
    return make_float2(a.x * b.x - a.y * b.y, a.x * b.y + a.y * b.x);
}

// Precompute twiddle tables into workspace:
//   tw[m]  = e^{-i pi m/1024}, m<1024   (all Stockham stage twiddles + final r2)
//   f3[k]  = e^{-i pi k/8192}, k<2048   (final DCT half-shift)
//   f23[k] = e^{-i 5 pi k/8192}        (= e2*e3, folded untangle twiddle)
__global__ void twprep(float2* __restrict__ tw, float2* __restrict__ f3,
                       float2* __restrict__ f23) {
    const int i = blockIdx.x * 256 + threadIdx.x;   // 0..2047
    float s, c;
    if (i < 1024) {
        sincosf(-PI_F * (float)i / 1024.0f, &s, &c);
        tw[i] = make_float2(c, s);
    }
    sincosf(-PI_F * (float)i / 8192.0f, &s, &c);
    f3[i] = make_float2(c, s);
    sincosf(-PI_F * 5.0f * (float)i / 8192.0f, &s, &c);
    f23[i] = make_float2(c, s);
}

// y[row] = orthonormal DST-II_4096(x[row]) + bias.
// Verified pipeline (rounds 11-13) with two fusions:
//  - stage 0 (all twiddles == 1) fused with the global gather (reg butterfly)
//  - final radix-2 fused into the untangle (Z rebuilt from V on the fly)
// 5 sync phases per row instead of 7.
__global__ __launch_bounds__(512) void dst_row(const float* __restrict__ x,
                                               const float* __restrict__ bias,
                                               const float2* __restrict__ twg,
                                               const float2* __restrict__ f3,
                                               const float2* __restrict__ f23,
                                               float* __restrict__ out) {
    __shared__ float2 U[2176], V[2176];   // padded 2048-complex ping-pong
    __shared__ float2 TW[1024];
    const int t = threadIdx.x;
    const int row = blockIdx.x;
    const float* xr = x + (size_t)row * IN_F;
    float* yr = out + (size_t)row * OUT_F;

    // ---- stage 0 fused with gather: m in {t, t+512, t+1024, t+1536};
    // j==0 so u=u2=(1,0) (verified: radix-4 butterfly w/ unit twiddles) ----
    {
        const float4 v0 = *(const float4*)(xr + 4 * t);               // m=t      (<1024)
        const float4 v1 = *(const float4*)(xr + 4 * (t + 512));       // m=t+512  (<1024)
        const float4 v2 = *(const float4*)(xr + (4092 - 4 * t));      // m=t+1024 (>=1024)
        const float4 v3 = *(const float4*)(xr + (2044 - 4 * t));      // m=t+1536 (>=1024)
        const float2 x0 = make_float2(v0.x, v0.z);
        const float2 x1 = make_float2(v1.x, v1.z);
        const float2 x2 = make_float2(-v2.w, -v2.y);
        const float2 x3 = make_float2(-v3.w, -v3.y);
        const float2 E = make_float2(x0.x + x2.x, x0.y + x2.y);
        const float2 G = make_float2(x0.x - x2.x, x0.y - x2.y);
        const float2 F = make_float2(x1.x + x3.x, x1.y + x3.y);
        const float2 H = make_float2(x1.x - x3.x, x1.y - x3.y);
        V[PD(t)]        = make_float2(E.x + F.x, E.y + F.y);
        V[PD(t + 1024)] = make_float2(E.x - F.x, E.y - F.y);
        V[PD(t + 512)]  = make_float2(G.x + H.y, G.y - H.x);   // G - iH
        V[PD(t + 1536)] = make_float2(G.x - H.y, G.y + H.x);   // G + iH
        // TW load rides under stage 0 (stage 0 itself doesn't use TW)
        TW[t] = twg[t];
        TW[t + 512] = twg[t + 512];
    }
    __syncthreads();

    // ---- radix-4 Stockham stages p=1..4 (verified round 12/13) ----
#pragma unroll
    for (int p = 1; p < 5; ++p) {
        const int s = 2 * p;
        const float2* src = (p & 1) ? V : U;
        float2* dst = (p & 1) ? U : V;
        {
            const int b = t;                         // 0..511
            const int j = b >> (9 - s);
            const int i2 = b & ((1 << (9 - s)) - 1);
            const int base = i2 + (j << (11 - s));
            const float2 x0 = src[PD(base)];
            const float2 x1 = src[PD(base + (1 << (9 - s)))];
            const float2 x2 = src[PD(base + (1 << (10 - s)))];
            const float2 x3 = src[PD(base + (1 << (10 - s)) + (1 << (9 - s)))];
            const float2 u  = TW[j << (9 - s)];
            const float2 u2 = TW[j << (10 - s)];
            const float2 t2 = cmul(u2, x2);
            const float2 t3 = cmul(u2, x3);
            const float2 E = make_float2(x0.x + t2.x, x0.y + t2.y);
            const float2 G = make_float2(x0.x - t2.x, x0.y - t2.y);
            const float2 F = make_float2(x1.x + t3.x, x1.y + t3.y);
            const float2 H = make_float2(x1.x - t3.x, x1.y - t3.y);
            const float2 uF = cmul(u, F);
            const float2 uH = cmul(u, H);
            dst[PD(b)]        = make_float2(E.x + uF.x, E.y + uF.y);
            dst[PD(b + 1024)] = make_float2(E.x - uF.x, E.y - uF.y);
            dst[PD(b + 512)]  = make_float2(G.x + uH.y, G.y - uH.x);  // G - i uH
            dst[PD(b + 1536)] = make_float2(G.x - uH.y, G.y + uH.x);  // G + i uH
        }
        __syncthreads();
    }
    // after p=4 (even), data in V; Z[k] = V[2k2] +/- TW[k2]*V[2k2+1], k2=k&1023

    // ---- untangle + r2-on-the-fly + twiddle + DST map (W = A*f3 + B*f23) ----
    const float amp1 = 2.0f * rsqrtf(8192.0f);
    const float amp0 = 2.0f * rsqrtf(16384.0f);
#pragma unroll
    for (int q = 0; q < 4; ++q) {
        const int k = t + q * 512;                   // 0..2047
        // Z[k] from V (fused final radix-2; branch uniform per q)
        const int k2 = k & 1023;
        const float2 a = V[PD(2 * k2)];
        const float2 c = V[PD(2 * k2 + 1)];
        const float2 wc = cmul(TW[k2], c);
        const float2 z = (k < 1024)
            ? make_float2(a.x + wc.x, a.y + wc.y)
            : make_float2(a.x - wc.x, a.y - wc.y);
        // Z[kc] from V
        const int kc = (2048 - k) & 2047;
        const int kck = kc & 1023;
        const float2 ac = V[PD(2 * kck)];
        const float2 cc = V[PD(2 * kck + 1)];
        const float2 wcc = cmul(TW[kck], cc);
        const float2 zc = (kc < 1024)
            ? make_float2(ac.x + wcc.x, ac.y + wcc.y)
            : make_float2(ac.x - wcc.x, ac.y - wcc.y);
        // untangle (verified round 11)
        const float Arr = 0.5f * (z.x + zc.x), Aii = 0.5f * (z.y - zc.y);
        const float Brr = 0.5f * (z.y + zc.y), Bii = 0.5f * (zc.x - z.x);
        const float2 e3 = f3[k];
        const float2 eA = f23[k];
        const float Wr = Arr * e3.x - Aii * e3.y + Brr * eA.x - Bii * eA.y;
        const float Wi = Arr * e3.y + Aii * e3.x + Brr * eA.y + Bii * eA.x;
        const int o1 = 4095 - k;
        yr[o1] = amp1 * Wr + bias[o1];
        if (k > 0) {
            const int o2 = k - 1;
            const float amp = (o2 == 0) ? amp0 : amp1;
            yr[o2] = amp * (-Wi) + bias[o2];
        } else {
            const float C2048 = (z.x - z.y) * 0.70710678118654752f;
            yr[2047] = amp1 * C2048 + bias[2047];
        }
    }
}

// Fallback (round-11 kernel, HW-verified): used only if ws is too small for tables.
__global__ __launch_bounds__(256) void dst_row_fb(const float* __restrict__ x,
                                                  const float* __restrict__ bias,
                                                  float* __restrict__ out) {
    __shared__ float Ar[2048], Ai[2048], Br[2048], Bi[2048];
    const int t = threadIdx.x;
    const int row = blockIdx.x;
    const float* xr = x + (size_t)row * IN_F;
    float* yr = out + (size_t)row * OUT_F;
#pragma unroll
    for (int q = 0; q < 8; ++q) {
        const int m = t + q * 256;
        float re, im;
        if (m < 1024) {
            const float4 v = *(const float4*)(xr + 4 * m);
            re = v.x; im = v.z;
        } else {
            const float4 v = *(const float4*)(xr + (8188 - 4 * m));
            re = -v.w; im = -v.y;
        }
        Ar[m] = re; Ai[m] = im;
    }
    __syncthreads();
    float *sr = Ar, *si = Ai, *dr = Br, *di = Bi;
    for (int s = 0; s < 11; ++s) {
        const int mm = 1024 >> s;
#pragma unroll
        for (int q = 0; q < 4; ++q) {
            const int b = t + q * 256;
            const int j = b >> (10 - s);
            const int i = b & (mm - 1);
            const int i0 = i + j * 2 * mm;
            const float ar = sr[i0], aim = si[i0];
            const float cr = sr[i0 + mm], ci = si[i0 + mm];
            float sw, cw;
            __sincosf(-PI_F * (float)j / (float)(1 << s), &sw, &cw);
            const float wr = cr * cw - ci * sw;
            const float wi = cr * sw + ci * cw;
            const int o0 = i + j * mm;
            dr[o0] = ar + wr;        di[o0] = aim + wi;
            dr[o0 + 1024] = ar - wr; di[o0 + 1024] = aim - wi;
        }
        __syncthreads();
        float* tp;
        tp = sr; sr = dr; dr = tp;
        tp = si; si = di; di = tp;
    }
    const float amp1 = 2.0f * rsqrtf(8192.0f);
    const float amp0 = 2.0f * rsqrtf(16384.0f);
#pragma unroll
    for (int q = 0; q < 8; ++q) {
        const int k = t + q * 256;
        const float zr = sr[k], zi = si[k];
        const int kc = (2048 - k) & 2047;
        const float cr = sr[kc], ci = si[kc];
        const float Arr = 0.5f * (zr + cr), Aii = 0.5f * (zi - ci);
        const float Brr = 0.5f * (zi + ci), Bii = 0.5f * (cr - zr);
        float s2, c2;
        __sincosf(-PI_F * (float)k / 2048.0f, &s2, &c2);
        const float Vr = Arr + Brr * c2 - Bii * s2;
        const float Vi = Aii + Brr * s2 + Bii * c2;
        float s3, c3;
        __sincosf(-PI_F * (float)k / 8192.0f, &s3, &c3);
        const float Wr = Vr * c3 - Vi * s3;
        const float Wi = Vr * s3 + Vi * c3;
        const int o1 = 4095 - k;
        yr[o1] = amp1 * Wr + bias[o1];
        if (k > 0) {
            const int o2 = k - 1;
            const float amp = (o2 == 0) ? amp0 : amp1;
            yr[o2] = amp * (-Wi) + bias[o2];
        } else {
            const float C2048 = (zr - zi) * 0.70710678118654752f;
            yr[2047] = amp1 * C2048 + bias[2047];
        }
    }
}

extern "C" void kernel_launch(void* const* d_in, const int* in_sizes, int n_in,
                              void* d_out, int out_size, void* d_ws, size_t ws_size,
                              hipStream_t stream) {
    const float* x    = (const float*)d_in[0];
    const float* bias = (const float*)d_in[2];
    float* out = (float*)d_out;

    if (ws_size >= 40960) {
        float2* tw  = (float2*)d_ws;                       // 1024 (8 KB)
        float2* f3  = (float2*)((char*)d_ws + 8192);       // 2048 (16 KB)
        float2* f23 = (float2*)((char*)d_ws + 24576);      // 2048 (16 KB)
        twprep<<<8, 256, 0, stream>>>(tw, f3, f23);
        dst_row<<<NROWS, 512, 0, stream>>>(x, bias, tw, f3, f23, out);
    } else {
        dst_row_fb<<<NROWS, 256, 0, stream>>>(x, bias, out);
    }
}

// Round 15
// 79.159 us; speedup vs baseline: 1.0211x; 1.0211x over previous
//
#include <hip/hip_runtime.h>
#include <cstdint>
#include <cstddef>

#define IN_F 4096
#define OUT_F 4096
#define NROWS 8192
#define PI_F 3.14159265358979323846f

// padded complex index (breaks power-of-2 bank strides; injective)
#define PD(a) ((a) + ((a) >> 4))

__device__ inline float2 cmul(float2 a, float2 b) {
    return make_float2(a.x * b.x - a.y * b.y, a.x * b.y + a.y * b.x);
}

// Precompute twiddle tables into workspace:
//   tw[m]  = e^{-i pi m/1024}, m<1024   (all Stockham stage twiddles + final r2)
//   f3[k]  = e^{-i pi k/8192}, k<2048   (final DCT half-shift)
//   f23[k] = e^{-i 5 pi k/8192}        (= e2*e3, folded untangle twiddle)
__global__ void twprep(float2* __restrict__ tw, float2* __restrict__ f3,
                       float2* __restrict__ f23) {
    const int i = blockIdx.x * 256 + threadIdx.x;   // 0..2047
    float s, c;
    if (i < 1024) {
        sincosf(-PI_F * (float)i / 1024.0f, &s, &c);
        tw[i] = make_float2(c, s);
    }
    sincosf(-PI_F * (float)i / 8192.0f, &s, &c);
    f3[i] = make_float2(c, s);
    sincosf(-PI_F * 5.0f * (float)i / 8192.0f, &s, &c);
    f23[i] = make_float2(c, s);
}

// Radix-4 Stockham stage body (verified rounds 12-14), one butterfly b=t.
__device__ __forceinline__ void r4stage(const float2* __restrict__ src,
                                        float2* __restrict__ dst,
                                        const float2* __restrict__ TW,
                                        int t, int s) {
    const int j = t >> (9 - s);
    const int i2 = t & ((1 << (9 - s)) - 1);
    const int base = i2 + (j << (11 - s));
    const float2 x0 = src[PD(base)];
    const float2 x1 = src[PD(base + (1 << (9 - s)))];
    const float2 x2 = src[PD(base + (1 << (10 - s)))];
    const float2 x3 = src[PD(base + (1 << (10 - s)) + (1 << (9 - s)))];
    const float2 u  = TW[j << (9 - s)];
    const float2 u2 = TW[j << (10 - s)];
    const float2 t2 = cmul(u2, x2);
    const float2 t3 = cmul(u2, x3);
    const float2 E = make_float2(x0.x + t2.x, x0.y + t2.y);
    const float2 G = make_float2(x0.x - t2.x, x0.y - t2.y);
    const float2 F = make_float2(x1.x + t3.x, x1.y + t3.y);
    const float2 H = make_float2(x1.x - t3.x, x1.y - t3.y);
    const float2 uF = cmul(u, F);
    const float2 uH = cmul(u, H);
    dst[PD(t)]        = make_float2(E.x + uF.x, E.y + uF.y);
    dst[PD(t + 1024)] = make_float2(E.x - uF.x, E.y - uF.y);
    dst[PD(t + 512)]  = make_float2(G.x + uH.y, G.y - uH.x);  // G - i uH
    dst[PD(t + 1536)] = make_float2(G.x - uH.y, G.y + uH.x);  // G + i uH
}

// Stage-0-fused gather (verified round 14): unit twiddles, global -> V.
__device__ __forceinline__ void gather0(const float* __restrict__ xr,
                                        float2* __restrict__ V, int t) {
    const float4 v0 = *(const float4*)(xr + 4 * t);
    const float4 v1 = *(const float4*)(xr + 4 * (t + 512));
    const float4 v2 = *(const float4*)(xr + (4092 - 4 * t));
    const float4 v3 = *(const float4*)(xr + (2044 - 4 * t));
    const float2 x0 = make_float2(v0.x, v0.z);
    const float2 x1 = make_float2(v1.x, v1.z);
    const float2 x2 = make_float2(-v2.w, -v2.y);
    const float2 x3 = make_float2(-v3.w, -v3.y);
    const float2 E = make_float2(x0.x + x2.x, x0.y + x2.y);
    const float2 G = make_float2(x0.x - x2.x, x0.y - x2.y);
    const float2 F = make_float2(x1.x + x3.x, x1.y + x3.y);
    const float2 H = make_float2(x1.x - x3.x, x1.y - x3.y);
    V[PD(t)]        = make_float2(E.x + F.x, E.y + F.y);
    V[PD(t + 1024)] = make_float2(E.x - F.x, E.y - F.y);
    V[PD(t + 512)]  = make_float2(G.x + H.y, G.y - H.x);   // G - iH
    V[PD(t + 1536)] = make_float2(G.x - H.y, G.y + H.x);   // G + iH
}

// Fused final-r2 Z reconstruction (verified round 14).
__device__ __forceinline__ float2 getZ(const float2* __restrict__ V,
                                       float2 twv, int k, int k2) {
    const float2 a = V[PD(2 * k2)];
    const float2 c = V[PD(2 * k2 + 1)];
    const float2 wc = cmul(twv, c);
    return (k < 1024) ? make_float2(a.x + wc.x, a.y + wc.y)
                      : make_float2(a.x - wc.x, a.y - wc.y);
}

// y[row] = orthonormal DST-II_4096(x[row]) + bias. TWO rows per block:
// same verified pipeline instantiated for rows A and B; barriers amortized,
// per-thread ILP doubled (independent butterfly chains).
__global__ __launch_bounds__(512) void dst_row(const float* __restrict__ x,
                                               const float* __restrict__ bias,
                                               const float2* __restrict__ twg,
                                               const float2* __restrict__ f3,
                                               const float2* __restrict__ f23,
                                               float* __restrict__ out) {
    __shared__ float2 UA[2176], VA[2176], UB[2176], VB[2176];  // 69.6 KB
    __shared__ float2 TW[1024];                                // 8 KB
    const int t = threadIdx.x;
    const int row0 = blockIdx.x * 2;
    const float* xr0 = x + (size_t)row0 * IN_F;
    const float* xr1 = xr0 + IN_F;
    float* yr0 = out + (size_t)row0 * OUT_F;
    float* yr1 = yr0 + OUT_F;

    // ---- phase 0: fused gather+stage0 for both rows; TW load rides along ----
    gather0(xr0, VA, t);
    gather0(xr1, VB, t);
    TW[t] = twg[t];
    TW[t + 512] = twg[t + 512];
    __syncthreads();

    // ---- radix-4 Stockham stages p=1..4, both rows per phase ----
#pragma unroll
    for (int p = 1; p < 5; ++p) {
        const int s = 2 * p;
        if (p & 1) { r4stage(VA, UA, TW, t, s); r4stage(VB, UB, TW, t, s); }
        else       { r4stage(UA, VA, TW, t, s); r4stage(UB, VB, TW, t, s); }
        __syncthreads();
    }
    // data in VA/VB; Z[k] = V[2k2] +/- TW[k2]*V[2k2+1]

    // ---- untangle + r2-on-the-fly + DST map, both rows (shared tables) ----
    const float amp1 = 2.0f * rsqrtf(8192.0f);
    const float amp0 = 2.0f * rsqrtf(16384.0f);
#pragma unroll
    for (int q = 0; q < 4; ++q) {
        const int k = t + q * 512;                   // 0..2047
        const int k2 = k & 1023;
        const int kc = (2048 - k) & 2047;
        const int kck = kc & 1023;
        const float2 tw2 = TW[k2];
        const float2 twc = TW[kck];
        const float2 e3 = f3[k];
        const float2 eA = f23[k];
        const int o1 = 4095 - k;
        const float b1v = bias[o1];
        const int o2 = (k > 0) ? (k - 1) : 2047;
        const float b2v = bias[o2];
        const float amp2 = (o2 == 0) ? amp0 : amp1;

        // row A
        {
            const float2 z = getZ(VA, tw2, k, k2);
            const float2 zc = getZ(VA, twc, kc, kck);
            const float Arr = 0.5f * (z.x + zc.x), Aii = 0.5f * (z.y - zc.y);
            const float Brr = 0.5f * (z.y + zc.y), Bii = 0.5f * (zc.x - z.x);
            const float Wr = Arr * e3.x - Aii * e3.y + Brr * eA.x - Bii * eA.y;
            const float Wi = Arr * e3.y + Aii * e3.x + Brr * eA.y + Bii * eA.x;
            yr0[o1] = amp1 * Wr + b1v;
            if (k > 0) {
                yr0[o2] = amp2 * (-Wi) + b2v;
            } else {
                const float C2048 = (z.x - z.y) * 0.70710678118654752f;
                yr0[2047] = amp1 * C2048 + b2v;
            }
        }
        // row B
        {
            const float2 z = getZ(VB, tw2, k, k2);
            const float2 zc = getZ(VB, twc, kc, kck);
            const float Arr = 0.5f * (z.x + zc.x), Aii = 0.5f * (z.y - zc.y);
            const float Brr = 0.5f * (z.y + zc.y), Bii = 0.5f * (zc.x - z.x);
            const float Wr = Arr * e3.x - Aii * e3.y + Brr * eA.x - Bii * eA.y;
            const float Wi = Arr * e3.y + Aii * e3.x + Brr * eA.y + Bii * eA.x;
            yr1[o1] = amp1 * Wr + b1v;
            if (k > 0) {
                yr1[o2] = amp2 * (-Wi) + b2v;
            } else {
                const float C2048 = (z.x - z.y) * 0.70710678118654752f;
                yr1[2047] = amp1 * C2048 + b2v;
            }
        }
    }
}

// Fallback (round-11 kernel, HW-verified): used only if ws is too small for tables.
__global__ __launch_bounds__(256) void dst_row_fb(const float* __restrict__ x,
                                                  const float* __restrict__ bias,
                                                  float* __restrict__ out) {
    __shared__ float Ar[2048], Ai[2048], Br[2048], Bi[2048];
    const int t = threadIdx.x;
    const int row = blockIdx.x;
    const float* xr = x + (size_t)row * IN_F;
    float* yr = out + (size_t)row * OUT_F;
#pragma unroll
    for (int q = 0; q < 8; ++q) {
        const int m = t + q * 256;
        float re, im;
        if (m < 1024) {
            const float4 v = *(const float4*)(xr + 4 * m);
            re = v.x; im = v.z;
        } else {
            const float4 v = *(const float4*)(xr + (8188 - 4 * m));
            re = -v.w; im = -v.y;
        }
        Ar[m] = re; Ai[m] = im;
    }
    __syncthreads();
    float *sr = Ar, *si = Ai, *dr = Br, *di = Bi;
    for (int s = 0; s < 11; ++s) {
        const int mm = 1024 >> s;
#pragma unroll
        for (int q = 0; q < 4; ++q) {
            const int b = t + q * 256;
            const int j = b >> (10 - s);
            const int i = b & (mm - 1);
            const int i0 = i + j * 2 * mm;
            const float ar = sr[i0], aim = si[i0];
            const float cr = sr[i0 + mm], ci = si[i0 + mm];
            float sw, cw;
            __sincosf(-PI_F * (float)j / (float)(1 << s), &sw, &cw);
            const float wr = cr * cw - ci * sw;
            const float wi = cr * sw + ci * cw;
            const int o0 = i + j * mm;
            dr[o0] = ar + wr;        di[o0] = aim + wi;
            dr[o0 + 1024] = ar - wr; di[o0 + 1024] = aim - wi;
        }
        __syncthreads();
        float* tp;
        tp = sr; sr = dr; dr = tp;
        tp = si; si = di; di = tp;
    }
    const float amp1 = 2.0f * rsqrtf(8192.0f);
    const float amp0 = 2.0f * rsqrtf(16384.0f);
#pragma unroll
    for (int q = 0; q < 8; ++q) {
        const int k = t + q * 256;
        const float zr = sr[k], zi = si[k];
        const int kc = (2048 - k) & 2047;
        const float cr = sr[kc], ci = si[kc];
        const float Arr = 0.5f * (zr + cr), Aii = 0.5f * (zi - ci);
        const float Brr = 0.5f * (zi + ci), Bii = 0.5f * (cr - zr);
        float s2, c2;
        __sincosf(-PI_F * (float)k / 2048.0f, &s2, &c2);
        const float Vr = Arr + Brr * c2 - Bii * s2;
        const float Vi = Aii + Brr * s2 + Bii * c2;
        float s3, c3;
        __sincosf(-PI_F * (float)k / 8192.0f, &s3, &c3);
        const float Wr = Vr * c3 - Vi * s3;
        const float Wi = Vr * s3 + Vi * c3;
        const int o1 = 4095 - k;
        yr[o1] = amp1 * Wr + bias[o1];
        if (k > 0) {
            const int o2 = k - 1;
            const float amp = (o2 == 0) ? amp0 : amp1;
            yr[o2] = amp * (-Wi) + bias[o2];
        } else {
            const float C2048 = (zr - zi) * 0.70710678118654752f;
            yr[2047] = amp1 * C2048 + bias[2047];
        }
    }
}

extern "C" void kernel_launch(void* const* d_in, const int* in_sizes, int n_in,
                              void* d_out, int out_size, void* d_ws, size_t ws_size,
                              hipStream_t stream) {
    const float* x    = (const float*)d_in[0];
    const float* bias = (const float*)d_in[2];
    float* out = (float*)d_out;

    if (ws_size >= 40960) {
        float2* tw  = (float2*)d_ws;                       // 1024 (8 KB)
        float2* f3  = (float2*)((char*)d_ws + 8192);       // 2048 (16 KB)
        float2* f23 = (float2*)((char*)d_ws + 24576);      // 2048 (16 KB)
        twprep<<<8, 256, 0, stream>>>(tw, f3, f23);
        dst_row<<<NROWS / 2, 512, 0, stream>>>(x, bias, tw, f3, f23, out);
    } else {
        dst_row_fb<<<NROWS, 256, 0, stream>>>(x, bias, out);
    }
}